// Round 2
// baseline (2409.010 us; speedup 1.0000x reference)
//
#include <hip/hip_runtime.h>

#define TOKN 65536   // 128*512
#define SQ 512
#define BB 128
#define DD 100
#define APAD 132

typedef unsigned short bf16t;
__device__ __forceinline__ float bf2f(bf16t v) {
  unsigned u = ((unsigned)v) << 16;
  return __uint_as_float(u);
}
__device__ __forceinline__ bf16t f2bf(float x) {
  unsigned u = __float_as_uint(x);
  unsigned r = u + 0x7FFFu + ((u >> 16) & 1u);
  return (bf16t)(r >> 16);
}
__device__ __forceinline__ float ldf(const float* p) { return *p; }
__device__ __forceinline__ float ldf(const bf16t* p) { return bf2f(*p); }

__device__ __forceinline__ float sigm(float x) { return 1.f / (1.f + __expf(-x)); }
__device__ __forceinline__ float tanhx(float x) { return 1.f - 2.f / (1.f + __expf(2.f * x)); }

// ---------------- embedding + mask ----------------
__global__ __launch_bounds__(256) void embed_kernel(
    const int* __restrict__ x1, const int* __restrict__ x2,
    const float* __restrict__ emb,
    float* __restrict__ e1, float* __restrict__ e2,
    float* __restrict__ m1, float* __restrict__ m2) {
  const int which = blockIdx.y;
  const int* __restrict__ x = which ? x2 : x1;
  float* __restrict__ e = which ? e2 : e1;
  float* __restrict__ m = which ? m2 : m1;
  int idx = blockIdx.x * 256 + threadIdx.x;
  if (idx >= TOKN * 50) return;
  int t = idx / 50;
  int d = idx - t * 50;
  int tok = x[t];
  float mk = (tok != 0) ? 1.f : 0.f;
  e[idx] = emb[tok * 50 + d] * mk;
  if (d == 0) m[t] = mk;
}

// ---------------- xz = A @ Wx + b for 4 combos (inp x dir) ----------------
// A: [TOKN, K] row-major (float or bf16); W: [K,200]; out: [combo][TOKN][200] bf16
template <int K, typename TI>
__global__ __launch_bounds__(256) void xz_gemm(
    const TI* __restrict__ A1, const TI* __restrict__ A2,
    const float* __restrict__ Wf, const float* __restrict__ bf_,
    const float* __restrict__ Wb, const float* __restrict__ bb_,
    bf16t* __restrict__ out) {
  const int combo = blockIdx.y;
  const TI* __restrict__ A = (combo < 2) ? A1 : A2;
  const float* __restrict__ W = (combo & 1) ? Wb : Wf;
  const float* __restrict__ bias = (combo & 1) ? bb_ : bf_;
  bf16t* __restrict__ O = out + (size_t)combo * ((size_t)TOKN * 200);
  const int t0 = blockIdx.x * 32;
  const int j = threadIdx.x;
  if (j >= 200) return;
  float acc[32];
  float bj = bias[j];
#pragma unroll
  for (int r = 0; r < 32; ++r) acc[r] = bj;
  const TI* __restrict__ Ab = A + (size_t)t0 * K;
  for (int kc = 0; kc < K; kc += 10) {
    float w[10];
#pragma unroll
    for (int kk = 0; kk < 10; ++kk) w[kk] = W[(kc + kk) * 200 + j];
#pragma unroll
    for (int r = 0; r < 32; ++r) {
#pragma unroll
      for (int kk = 0; kk < 10; ++kk)
        acc[r] += ldf(&Ab[r * K + kc + kk]) * w[kk];
    }
  }
#pragma unroll
  for (int r = 0; r < 32; ++r)
    O[(size_t)(t0 + r) * 200 + j] = f2bf(acc[r]);
}

// ---------------- LSTM scan: one block per (scan, batch) ----------------
// scan = inp*2 + dir.  Backward scan reads token S-1-t at step t, writes step t
// at feature offset 50 (Keras go_backwards: no output re-reversal).
__global__ __launch_bounds__(256) void lstm_scan(
    const bf16t* __restrict__ xz,
    const float* __restrict__ Whf, const float* __restrict__ Whb,
    bf16t* __restrict__ out1, bf16t* __restrict__ out2,
    const float* __restrict__ m1, const float* __restrict__ m2,
    int hasMask) {
  const int blk = blockIdx.x;
  const int scan = blk >> 7;
  const int b = blk & 127;
  const int inp = scan >> 1;
  const int dir = scan & 1;
  const float* __restrict__ Wh = dir ? Whb : Whf;
  const bf16t* __restrict__ xzs = xz + (size_t)scan * TOKN * 200 + (size_t)b * SQ * 200;
  bf16t* __restrict__ outp = (inp ? out2 : out1) + (size_t)b * SQ * 100 + dir * 50;
  const float* __restrict__ mk = (inp ? m2 : m1) + b * SQ;

  const int j = threadIdx.x;
  __shared__ __align__(16) float h_lds[50];
  __shared__ float act[200];
  float whc[50];
  if (j < 200) {
#pragma unroll
    for (int k = 0; k < 50; ++k) whc[k] = Wh[k * 200 + j];
  }
  if (j < 50) h_lds[j] = 0.f;
  float c = 0.f;
  float z0 = 0.f, z1 = 0.f;
  if (j < 200) {
    z0 = bf2f(xzs[(size_t)(dir ? (SQ - 1) : 0) * 200 + j]);
    z1 = bf2f(xzs[(size_t)(dir ? (SQ - 2) : 1) * 200 + j]);
  }
  __syncthreads();
  for (int t = 0; t < SQ; ++t) {
    int tp = (t + 2 < SQ) ? (t + 2) : (SQ - 1);
    int rowp = dir ? (SQ - 1 - tp) : tp;
    float znext = 0.f;
    if (j < 200) {
      znext = bf2f(xzs[(size_t)rowp * 200 + j]);
      float z = z0;
#pragma unroll
      for (int k = 0; k < 50; ++k) z += h_lds[k] * whc[k];
      float a = (j >= 100 && j < 150) ? tanhx(z) : sigm(z);
      act[j] = a;
    }
    __syncthreads();
    if (j < 50) {
      c = act[50 + j] * c + act[j] * act[100 + j];
      float hn = act[150 + j] * tanhx(c);
      h_lds[j] = hn;
      float mv = hasMask ? mk[t] : 1.f;
      outp[(size_t)t * 100 + j] = f2bf(hn * mv);
    }
    __syncthreads();
    z0 = z1;
    z1 = znext;
  }
}

// ---------------- attention (per timestep s): A=E1@E2^T, two softmaxes ----------------
__global__ __launch_bounds__(256) void attn_kernel(
    const bf16t* __restrict__ enc1, const bf16t* __restrict__ enc2,
    const float* __restrict__ m1, const float* __restrict__ m2,
    float* __restrict__ d1, float* __restrict__ d2) {
  const int s = blockIdx.x;
  const int tid = threadIdx.x;
  __shared__ __align__(16) float E1[BB][DD];
  __shared__ __align__(16) float E2[BB + 1][DD];  // +1 row pad for OOB-col reads
  __shared__ __align__(16) float Ah[64][APAD];
  __shared__ float mk1[BB], mk2[BB];
  __shared__ float rden[64];

  for (int idx = tid; idx < BB * DD; idx += 256) {
    int i = idx / DD, d = idx - i * DD;
    E1[i][d] = bf2f(enc1[((size_t)i * SQ + s) * DD + d]);
    E2[i][d] = bf2f(enc2[((size_t)i * SQ + s) * DD + d]);
  }
  if (tid < BB) {
    mk1[tid] = m1[tid * SQ + s];
    mk2[tid] = m2[tid * SQ + s];
  }
  __syncthreads();

  const int ti = tid >> 4, tjj = tid & 15;
  const int xj = tid & 127;
  const int xd0 = (tid >> 7) * 50;
  float N[50];
#pragma unroll
  for (int q = 0; q < 50; ++q) N[q] = 0.f;
  float Dacc = 0.f, M = -1e30f;

  for (int half = 0; half < 2; ++half) {
    const int r0 = half * 64;
    // --- GEMM1: A[i_local=4ti+ii][j=tjj+16jj] = E1[r0+i_local] . E2[j]
    float acc[4][8];
#pragma unroll
    for (int ii = 0; ii < 4; ++ii)
#pragma unroll
      for (int jj = 0; jj < 8; ++jj) acc[ii][jj] = 0.f;
    for (int k = 0; k < DD; k += 4) {
      float4 a4[4], b4[8];
#pragma unroll
      for (int ii = 0; ii < 4; ++ii)
        a4[ii] = *(const float4*)&E1[r0 + 4 * ti + ii][k];
#pragma unroll
      for (int jj = 0; jj < 8; ++jj)
        b4[jj] = *(const float4*)&E2[tjj + 16 * jj][k];
#pragma unroll
      for (int ii = 0; ii < 4; ++ii)
#pragma unroll
        for (int jj = 0; jj < 8; ++jj)
          acc[ii][jj] += a4[ii].x * b4[jj].x + a4[ii].y * b4[jj].y +
                         a4[ii].z * b4[jj].z + a4[ii].w * b4[jj].w;
    }
#pragma unroll
    for (int ii = 0; ii < 4; ++ii)
#pragma unroll
      for (int jj = 0; jj < 8; ++jj)
        Ah[4 * ti + ii][tjj + 16 * jj] = acc[ii][jj];
    __syncthreads();

    // --- x2 (beta) online accumulation over i, reads RAW scores
    {
      float lm = M;
      for (int i = 0; i < 64; ++i) lm = fmaxf(lm, Ah[i][xj]);
      float scale = __expf(M - lm);
      Dacc *= scale;
#pragma unroll
      for (int q = 0; q < 50; ++q) N[q] *= scale;
      for (int i = 0; i < 64; ++i) {
        float p = __expf(Ah[i][xj] - lm) * mk1[r0 + i];
        Dacc += p;
        const float2* e1p = (const float2*)&E1[r0 + i][xd0];
#pragma unroll
        for (int q = 0; q < 25; ++q) {
          float2 ev = e1p[q];
          N[2 * q] += p * ev.x;
          N[2 * q + 1] += p * ev.y;
        }
      }
      M = lm;
    }
    __syncthreads();

    // --- alpha row stats; overwrite Ah with p = exp(A - rowmax) * mk2[j]
    {
      int row = tid >> 2, seg = tid & 3;
      float mx = -1e30f;
      for (int q = 0; q < 32; ++q) mx = fmaxf(mx, Ah[row][seg + 4 * q]);
      mx = fmaxf(mx, __shfl_xor(mx, 1));
      mx = fmaxf(mx, __shfl_xor(mx, 2));
      float sm = 0.f;
      for (int q = 0; q < 32; ++q) {
        int jc = seg + 4 * q;
        float p = __expf(Ah[row][jc] - mx) * mk2[jc];
        Ah[row][jc] = p;
        sm += p;
      }
      sm += __shfl_xor(sm, 1);
      sm += __shfl_xor(sm, 2);
      if (seg == 0) rden[row] = sm + 1e-8f;
    }
    __syncthreads();

    // --- GEMM2: x1_dual rows r0.., cols d = tjj+16jj
    {
      float o[4][8];
#pragma unroll
      for (int ii = 0; ii < 4; ++ii)
#pragma unroll
        for (int jj = 0; jj < 8; ++jj) o[ii][jj] = 0.f;
      for (int jb = 0; jb < BB; ++jb) {
        float pv[4], ev[8];
#pragma unroll
        for (int ii = 0; ii < 4; ++ii) pv[ii] = Ah[4 * ti + ii][jb];
#pragma unroll
        for (int jj = 0; jj < 8; ++jj) ev[jj] = E2[jb][tjj + 16 * jj];
#pragma unroll
        for (int ii = 0; ii < 4; ++ii)
#pragma unroll
          for (int jj = 0; jj < 8; ++jj) o[ii][jj] += pv[ii] * ev[jj];
      }
#pragma unroll
      for (int ii = 0; ii < 4; ++ii) {
        int i = r0 + 4 * ti + ii;
        float inv = 1.f / rden[4 * ti + ii];
#pragma unroll
        for (int jj = 0; jj < 8; ++jj) {
          int d = tjj + 16 * jj;
          if (d < DD)
            d1[((size_t)i * SQ + s) * DD + d] = o[ii][jj] * inv;
        }
      }
    }
    __syncthreads();
  }
  float invD = 1.f / (Dacc + 1e-8f);
#pragma unroll
  for (int q = 0; q < 50; ++q)
    d2[((size_t)xj * SQ + s) * DD + xd0 + q] = N[q] * invD;
}

// ---------------- fused match+dense+relu: map = relu([e,d,e*d,e-d] @ W + b) ----------------
__global__ __launch_bounds__(256) void dense_kernel(
    const bf16t* __restrict__ enc1, const bf16t* __restrict__ enc2,
    const float* __restrict__ d1, const float* __restrict__ d2,
    const float* __restrict__ W, const float* __restrict__ bias,
    bf16t* __restrict__ map1, bf16t* __restrict__ map2) {
  const int inp = blockIdx.y;
  const bf16t* __restrict__ E = inp ? enc2 : enc1;
  const float* __restrict__ Dm = inp ? d2 : d1;
  bf16t* __restrict__ O = inp ? map2 : map1;
  const int t0 = blockIdx.x * 32;
  const int j = threadIdx.x & 127;
  const int g = threadIdx.x >> 7;  // k-half split
  __shared__ float partial[32][100];
  float acc[32];
#pragma unroll
  for (int r = 0; r < 32; ++r) acc[r] = 0.f;
  if (j < 100) {
    const int k0 = g * 50;
    for (int kc = 0; kc < 50; kc += 10) {
      float t1[10], t2[10], wP[10];
#pragma unroll
      for (int kk = 0; kk < 10; ++kk) {
        int k = k0 + kc + kk;
        float wE = W[k * 100 + j];
        float wD = W[(100 + k) * 100 + j];
        float wp = W[(200 + k) * 100 + j];
        float wM = W[(300 + k) * 100 + j];
        t1[kk] = wE + wM;
        t2[kk] = wD - wM;
        wP[kk] = wp;
      }
#pragma unroll
      for (int r = 0; r < 32; ++r) {
        const bf16t* Er = E + (size_t)(t0 + r) * 100 + k0 + kc;
        const float* Dr = Dm + (size_t)(t0 + r) * 100 + k0 + kc;
#pragma unroll
        for (int kk = 0; kk < 10; ++kk) {
          float e = bf2f(Er[kk]);
          float dv = Dr[kk];
          acc[r] += e * t1[kk] + dv * t2[kk] + (e * dv) * wP[kk];
        }
      }
    }
  }
  if (g == 1 && j < 100) {
#pragma unroll
    for (int r = 0; r < 32; ++r) partial[r][j] = acc[r];
  }
  __syncthreads();
  if (g == 0 && j < 100) {
#pragma unroll
    for (int r = 0; r < 32; ++r) {
      float v = acc[r] + partial[r][j] + bias[j];
      O[(size_t)(t0 + r) * 100 + j] = f2bf(fmaxf(v, 0.f));
    }
  }
}

// ---------------- masked pooling ----------------
__global__ __launch_bounds__(128) void pool_kernel(
    const bf16t* __restrict__ cmp1, const bf16t* __restrict__ cmp2,
    const float* __restrict__ m1, const float* __restrict__ m2,
    float* __restrict__ pooled) {
  int b = blockIdx.x & 127, inp = blockIdx.x >> 7;
  const bf16t* C = (inp ? cmp2 : cmp1) + (size_t)b * SQ * 100;
  const float* M = (inp ? m2 : m1) + b * SQ;
  int f = threadIdx.x;
  float ms = 0.f;
  for (int s = f; s < SQ; s += 128) ms += M[s];
  __shared__ float red[128];
  red[f] = ms;
  __syncthreads();
  for (int o = 64; o > 0; o >>= 1) {
    if (f < o) red[f] += red[f + o];
    __syncthreads();
  }
  float msum = red[0];
  if (f < 100) {
    float sm = 0.f, mx = -1e30f;
    for (int s = 0; s < SQ; ++s) {
      float v = bf2f(C[(size_t)s * 100 + f]) * M[s];
      sm += v;
      mx = fmaxf(mx, v);
    }
    pooled[b * 400 + inp * 200 + f] = sm / msum;
    pooled[b * 400 + inp * 200 + 100 + f] = mx;
  }
}

// ---------------- final MLP + softmax ----------------
__global__ __launch_bounds__(128) void final_kernel(
    const float* __restrict__ pooled, const float* __restrict__ W1,
    const float* __restrict__ b1, const float* __restrict__ W2,
    const float* __restrict__ b2, float* __restrict__ out) {
  int b = blockIdx.x;
  int j = threadIdx.x;
  __shared__ float pr[400];
  __shared__ float h[100];
  for (int idx = j; idx < 400; idx += 128) pr[idx] = pooled[b * 400 + idx];
  __syncthreads();
  if (j < 100) {
    float a = b1[j];
    for (int k = 0; k < 400; ++k) a += pr[k] * W1[k * 100 + j];
    h[j] = tanhx(a);
  }
  __syncthreads();
  if (j == 0) {
    float l0 = b2[0], l1 = b2[1];
    for (int k = 0; k < 100; ++k) {
      l0 += h[k] * W2[k * 2];
      l1 += h[k] * W2[k * 2 + 1];
    }
    float mx = fmaxf(l0, l1);
    float e0 = __expf(l0 - mx), e1 = __expf(l1 - mx);
    float inv = 1.f / (e0 + e1);
    out[b * 2] = e0 * inv;
    out[b * 2 + 1] = e1 * inv;
  }
}

extern "C" void kernel_launch(void* const* d_in, const int* in_sizes, int n_in,
                              void* d_out, int out_size, void* d_ws, size_t ws_size,
                              hipStream_t stream) {
  const int* x1 = (const int*)d_in[0];
  const int* x2 = (const int*)d_in[1];
  const float* emb = (const float*)d_in[2];
  const float* b1f_Wx = (const float*)d_in[3];
  const float* b1f_Wh = (const float*)d_in[4];
  const float* b1f_b = (const float*)d_in[5];
  const float* b1b_Wx = (const float*)d_in[6];
  const float* b1b_Wh = (const float*)d_in[7];
  const float* b1b_b = (const float*)d_in[8];
  const float* dense_W = (const float*)d_in[9];
  const float* dense_b = (const float*)d_in[10];
  const float* b2f_Wx = (const float*)d_in[11];
  const float* b2f_Wh = (const float*)d_in[12];
  const float* b2f_b = (const float*)d_in[13];
  const float* b2b_Wx = (const float*)d_in[14];
  const float* b2b_Wh = (const float*)d_in[15];
  const float* b2b_b = (const float*)d_in[16];
  const float* dense1_W = (const float*)d_in[17];
  const float* dense1_b = (const float*)d_in[18];
  const float* out_W = (const float*)d_in[19];
  const float* out_b = (const float*)d_in[20];
  float* out = (float*)d_out;

  // ---- workspace layout (~151 MB total) ----
  // region R0: xz  [4][TOKN][200] bf16 = 104.86 MB; d1/d2 (fp32, 52.4 MB) alias it
  //   (xz live gemm->scan; d live attn->dense; disjoint lifetimes)
  // region R1: enc1/enc2 [TOKN][100] bf16 each; e1/e2 (fp32 TOKN*50) alias
  //   (e live embed->gemm1; enc written by lstm1 afterwards)
  // region R2: map1/map2 [TOKN][100] bf16 each
  char* base = (char*)d_ws;
  bf16t* xz = (bf16t*)base;
  float* d1 = (float*)base;
  float* d2 = d1 + (size_t)TOKN * 100;
  char* r1 = base + (size_t)4 * TOKN * 200 * sizeof(bf16t);
  bf16t* enc1 = (bf16t*)r1;
  bf16t* enc2 = enc1 + (size_t)TOKN * 100;
  float* e1 = (float*)r1;
  float* e2 = e1 + (size_t)TOKN * 50;
  bf16t* map1 = enc2 + (size_t)TOKN * 100;
  bf16t* map2 = map1 + (size_t)TOKN * 100;
  float* m1 = (float*)(map2 + (size_t)TOKN * 100);
  float* m2 = m1 + TOKN;
  float* pooled = m2 + TOKN;
  bf16t* cmp1 = enc1;  // alias: enc dead after dense
  bf16t* cmp2 = enc2;
  (void)in_sizes; (void)n_in; (void)out_size; (void)ws_size;

  embed_kernel<<<dim3((TOKN * 50 + 255) / 256, 2), 256, 0, stream>>>(
      x1, x2, emb, e1, e2, m1, m2);
  xz_gemm<50, float><<<dim3(TOKN / 32, 4), 256, 0, stream>>>(
      e1, e2, b1f_Wx, b1f_b, b1b_Wx, b1b_b, xz);
  lstm_scan<<<512, 256, 0, stream>>>(xz, b1f_Wh, b1b_Wh, enc1, enc2, m1, m2, 1);
  attn_kernel<<<SQ, 256, 0, stream>>>(enc1, enc2, m1, m2, d1, d2);
  dense_kernel<<<dim3(TOKN / 32, 2), 256, 0, stream>>>(
      enc1, enc2, d1, d2, dense_W, dense_b, map1, map2);
  xz_gemm<100, bf16t><<<dim3(TOKN / 32, 4), 256, 0, stream>>>(
      map1, map2, b2f_Wx, b2f_b, b2b_Wx, b2b_b, xz);
  lstm_scan<<<512, 256, 0, stream>>>(xz, b2f_Wh, b2b_Wh, cmp1, cmp2, m1, m2, 0);
  pool_kernel<<<256, 128, 0, stream>>>(cmp1, cmp2, m1, m2, pooled);
  final_kernel<<<128, 128, 0, stream>>>(pooled, dense1_W, dense1_b, out_W, out_b, out);
}

// Round 3
// 1807.706 us; speedup vs baseline: 1.3326x; 1.3326x over previous
//
#include <hip/hip_runtime.h>

#define TOKN 65536   // 128*512
#define SQ 512
#define BB 128
#define DD 100
#define APAD 132

typedef unsigned short bf16t;
__device__ __forceinline__ float bf2f(bf16t v) {
  unsigned u = ((unsigned)v) << 16;
  return __uint_as_float(u);
}
__device__ __forceinline__ bf16t f2bf(float x) {
  unsigned u = __float_as_uint(x);
  unsigned r = u + 0x7FFFu + ((u >> 16) & 1u);
  return (bf16t)(r >> 16);
}
// load 2 consecutive elements as floats
__device__ __forceinline__ float2 ldpair(const float* p) { return *(const float2*)p; }
__device__ __forceinline__ float2 ldpair(const bf16t* p) {
  unsigned u = *(const unsigned*)p;
  float2 r;
  r.x = __uint_as_float(u << 16);
  r.y = __uint_as_float(u & 0xFFFF0000u);
  return r;
}

__device__ __forceinline__ float sigm(float x) { return 1.f / (1.f + __expf(-x)); }
__device__ __forceinline__ float tanhx(float x) { return 1.f - 2.f / (1.f + __expf(2.f * x)); }

// ---------------- embedding + mask ----------------
__global__ __launch_bounds__(256) void embed_kernel(
    const int* __restrict__ x1, const int* __restrict__ x2,
    const float* __restrict__ emb,
    float* __restrict__ e1, float* __restrict__ e2,
    float* __restrict__ m1, float* __restrict__ m2) {
  const int which = blockIdx.y;
  const int* __restrict__ x = which ? x2 : x1;
  float* __restrict__ e = which ? e2 : e1;
  float* __restrict__ m = which ? m2 : m1;
  int idx = blockIdx.x * 256 + threadIdx.x;
  if (idx >= TOKN * 50) return;
  int t = idx / 50;
  int d = idx - t * 50;
  int tok = x[t];
  float mk = (tok != 0) ? 1.f : 0.f;
  e[idx] = emb[tok * 50 + d] * mk;
  if (d == 0) m[t] = mk;
}

// ---------------- xz = A @ Wx + b for 4 combos (inp x dir) ----------------
// A: [TOKN, K] row-major (float or bf16); W: [K,200]; out: [combo][TOKN][200] bf16
// 16 token-rows per block; thread j owns output column j; weights L2-resident,
// A-row loads are block-uniform (broadcast).  acc[16] keeps VGPR low.
template <int K, typename TI>
__global__ __launch_bounds__(256) void xz_gemm(
    const TI* __restrict__ A1, const TI* __restrict__ A2,
    const float* __restrict__ Wf, const float* __restrict__ bf_,
    const float* __restrict__ Wb, const float* __restrict__ bb_,
    bf16t* __restrict__ out) {
  const int combo = blockIdx.y;
  const TI* __restrict__ A = (combo < 2) ? A1 : A2;
  const float* __restrict__ W = (combo & 1) ? Wb : Wf;
  const float* __restrict__ bias = (combo & 1) ? bb_ : bf_;
  bf16t* __restrict__ O = out + (size_t)combo * ((size_t)TOKN * 200);
  const int t0 = blockIdx.x * 16;
  const int j = threadIdx.x;
  if (j >= 200) return;
  float acc[16];
  float bj = bias[j];
#pragma unroll
  for (int r = 0; r < 16; ++r) acc[r] = bj;
  const TI* __restrict__ Ab = A + (size_t)t0 * K;
  for (int k2 = 0; k2 < K / 2; ++k2) {
    float w0 = W[(2 * k2) * 200 + j];
    float w1 = W[(2 * k2 + 1) * 200 + j];
#pragma unroll
    for (int r = 0; r < 16; ++r) {
      float2 a = ldpair(Ab + r * K + 2 * k2);
      acc[r] = fmaf(a.x, w0, acc[r]);
      acc[r] = fmaf(a.y, w1, acc[r]);
    }
  }
#pragma unroll
  for (int r = 0; r < 16; ++r)
    O[(size_t)(t0 + r) * 200 + j] = f2bf(acc[r]);
}

// ---------------- LSTM scan: one block per (scan, batch) ----------------
// scan = inp*2 + dir.  Backward scan reads token S-1-t at step t, writes step t
// at feature offset 50 (Keras go_backwards: no output re-reversal).
__global__ __launch_bounds__(256) void lstm_scan(
    const bf16t* __restrict__ xz,
    const float* __restrict__ Whf, const float* __restrict__ Whb,
    bf16t* __restrict__ out1, bf16t* __restrict__ out2,
    const float* __restrict__ m1, const float* __restrict__ m2,
    int hasMask) {
  const int blk = blockIdx.x;
  const int scan = blk >> 7;
  const int b = blk & 127;
  const int inp = scan >> 1;
  const int dir = scan & 1;
  const float* __restrict__ Wh = dir ? Whb : Whf;
  const bf16t* __restrict__ xzs = xz + (size_t)scan * TOKN * 200 + (size_t)b * SQ * 200;
  bf16t* __restrict__ outp = (inp ? out2 : out1) + (size_t)b * SQ * 100 + dir * 50;
  const float* __restrict__ mk = (inp ? m2 : m1) + b * SQ;

  const int j = threadIdx.x;
  __shared__ __align__(16) float h_lds[52];
  __shared__ float act[200];
  float whc[50];
  if (j < 200) {
#pragma unroll
    for (int k = 0; k < 50; ++k) whc[k] = Wh[k * 200 + j];
  }
  if (j < 52) h_lds[j] = 0.f;
  float c = 0.f;
  float z0 = 0.f, z1 = 0.f;
  if (j < 200) {
    z0 = bf2f(xzs[(size_t)(dir ? (SQ - 1) : 0) * 200 + j]);
    z1 = bf2f(xzs[(size_t)(dir ? (SQ - 2) : 1) * 200 + j]);
  }
  __syncthreads();
  for (int t = 0; t < SQ; ++t) {
    int tp = (t + 2 < SQ) ? (t + 2) : (SQ - 1);
    int rowp = dir ? (SQ - 1 - tp) : tp;
    float znext = 0.f;
    if (j < 200) {
      znext = bf2f(xzs[(size_t)rowp * 200 + j]);
      // 4 interleaved partial chains: dep latency 50*4 -> ~13*4 cyc
      float za = z0, zb = 0.f, zc = 0.f, zd = 0.f;
#pragma unroll
      for (int k = 0; k < 48; k += 4) {
        za = fmaf(h_lds[k], whc[k], za);
        zb = fmaf(h_lds[k + 1], whc[k + 1], zb);
        zc = fmaf(h_lds[k + 2], whc[k + 2], zc);
        zd = fmaf(h_lds[k + 3], whc[k + 3], zd);
      }
      za = fmaf(h_lds[48], whc[48], za);
      zb = fmaf(h_lds[49], whc[49], zb);
      float z = (za + zb) + (zc + zd);
      float a = (j >= 100 && j < 150) ? tanhx(z) : sigm(z);
      act[j] = a;
    }
    __syncthreads();
    if (j < 50) {
      c = act[50 + j] * c + act[j] * act[100 + j];
      float hn = act[150 + j] * tanhx(c);
      h_lds[j] = hn;
      float mv = hasMask ? mk[t] : 1.f;
      outp[(size_t)t * 100 + j] = f2bf(hn * mv);
    }
    __syncthreads();
    z0 = z1;
    z1 = znext;
  }
}

// ---------------- attention (per timestep s): A=E1@E2^T, two softmaxes ----------------
__global__ __launch_bounds__(256) void attn_kernel(
    const bf16t* __restrict__ enc1, const bf16t* __restrict__ enc2,
    const float* __restrict__ m1, const float* __restrict__ m2,
    float* __restrict__ d1, float* __restrict__ d2) {
  const int s = blockIdx.x;
  const int tid = threadIdx.x;
  __shared__ __align__(16) float E1[BB][DD];
  __shared__ __align__(16) float E2[BB + 1][DD];  // +1 row pad for OOB-col reads
  __shared__ __align__(16) float Ah[64][APAD];
  __shared__ float mk1[BB], mk2[BB];
  __shared__ float rden[64];

  for (int idx = tid; idx < BB * DD; idx += 256) {
    int i = idx / DD, d = idx - i * DD;
    E1[i][d] = bf2f(enc1[((size_t)i * SQ + s) * DD + d]);
    E2[i][d] = bf2f(enc2[((size_t)i * SQ + s) * DD + d]);
  }
  if (tid < BB) {
    mk1[tid] = m1[tid * SQ + s];
    mk2[tid] = m2[tid * SQ + s];
  }
  __syncthreads();

  const int ti = tid >> 4, tjj = tid & 15;
  const int xj = tid & 127;
  const int xd0 = (tid >> 7) * 50;
  float N[50];
#pragma unroll
  for (int q = 0; q < 50; ++q) N[q] = 0.f;
  float Dacc = 0.f, M = -1e30f;

  for (int half = 0; half < 2; ++half) {
    const int r0 = half * 64;
    // --- GEMM1: A[i_local=4ti+ii][j=tjj+16jj] = E1[r0+i_local] . E2[j]
    float acc[4][8];
#pragma unroll
    for (int ii = 0; ii < 4; ++ii)
#pragma unroll
      for (int jj = 0; jj < 8; ++jj) acc[ii][jj] = 0.f;
    for (int k = 0; k < DD; k += 4) {
      float4 a4[4], b4[8];
#pragma unroll
      for (int ii = 0; ii < 4; ++ii)
        a4[ii] = *(const float4*)&E1[r0 + 4 * ti + ii][k];
#pragma unroll
      for (int jj = 0; jj < 8; ++jj)
        b4[jj] = *(const float4*)&E2[tjj + 16 * jj][k];
#pragma unroll
      for (int ii = 0; ii < 4; ++ii)
#pragma unroll
        for (int jj = 0; jj < 8; ++jj)
          acc[ii][jj] += a4[ii].x * b4[jj].x + a4[ii].y * b4[jj].y +
                         a4[ii].z * b4[jj].z + a4[ii].w * b4[jj].w;
    }
#pragma unroll
    for (int ii = 0; ii < 4; ++ii)
#pragma unroll
      for (int jj = 0; jj < 8; ++jj)
        Ah[4 * ti + ii][tjj + 16 * jj] = acc[ii][jj];
    __syncthreads();

    // --- x2 (beta) online accumulation over i, reads RAW scores
    {
      float lm = M;
      for (int i = 0; i < 64; ++i) lm = fmaxf(lm, Ah[i][xj]);
      float scale = __expf(M - lm);
      Dacc *= scale;
#pragma unroll
      for (int q = 0; q < 50; ++q) N[q] *= scale;
      for (int i = 0; i < 64; ++i) {
        float p = __expf(Ah[i][xj] - lm) * mk1[r0 + i];
        Dacc += p;
        const float2* e1p = (const float2*)&E1[r0 + i][xd0];
#pragma unroll
        for (int q = 0; q < 25; ++q) {
          float2 ev = e1p[q];
          N[2 * q] += p * ev.x;
          N[2 * q + 1] += p * ev.y;
        }
      }
      M = lm;
    }
    __syncthreads();

    // --- alpha row stats; overwrite Ah with p = exp(A - rowmax) * mk2[j]
    {
      int row = tid >> 2, seg = tid & 3;
      float mx = -1e30f;
      for (int q = 0; q < 32; ++q) mx = fmaxf(mx, Ah[row][seg + 4 * q]);
      mx = fmaxf(mx, __shfl_xor(mx, 1));
      mx = fmaxf(mx, __shfl_xor(mx, 2));
      float sm = 0.f;
      for (int q = 0; q < 32; ++q) {
        int jc = seg + 4 * q;
        float p = __expf(Ah[row][jc] - mx) * mk2[jc];
        Ah[row][jc] = p;
        sm += p;
      }
      sm += __shfl_xor(sm, 1);
      sm += __shfl_xor(sm, 2);
      if (seg == 0) rden[row] = sm + 1e-8f;
    }
    __syncthreads();

    // --- GEMM2: x1_dual rows r0.., cols d = tjj+16jj
    {
      float o[4][8];
#pragma unroll
      for (int ii = 0; ii < 4; ++ii)
#pragma unroll
        for (int jj = 0; jj < 8; ++jj) o[ii][jj] = 0.f;
      for (int jb = 0; jb < BB; ++jb) {
        float pv[4], ev[8];
#pragma unroll
        for (int ii = 0; ii < 4; ++ii) pv[ii] = Ah[4 * ti + ii][jb];
#pragma unroll
        for (int jj = 0; jj < 8; ++jj) ev[jj] = E2[jb][tjj + 16 * jj];
#pragma unroll
        for (int ii = 0; ii < 4; ++ii)
#pragma unroll
          for (int jj = 0; jj < 8; ++jj) o[ii][jj] += pv[ii] * ev[jj];
      }
#pragma unroll
      for (int ii = 0; ii < 4; ++ii) {
        int i = r0 + 4 * ti + ii;
        float inv = 1.f / rden[4 * ti + ii];
#pragma unroll
        for (int jj = 0; jj < 8; ++jj) {
          int d = tjj + 16 * jj;
          if (d < DD)
            d1[((size_t)i * SQ + s) * DD + d] = o[ii][jj] * inv;
        }
      }
    }
    __syncthreads();
  }
  float invD = 1.f / (Dacc + 1e-8f);
#pragma unroll
  for (int q = 0; q < 50; ++q)
    d2[((size_t)xj * SQ + s) * DD + xd0 + q] = N[q] * invD;
}

// ---------------- fused match+dense+relu: map = relu([e,d,e*d,e-d] @ W + b) ----------------
// 16 token-rows per block, 128 threads (j<100 active), k processed in pairs.
__global__ __launch_bounds__(128) void dense_kernel(
    const bf16t* __restrict__ enc1, const bf16t* __restrict__ enc2,
    const float* __restrict__ d1, const float* __restrict__ d2,
    const float* __restrict__ W, const float* __restrict__ bias,
    bf16t* __restrict__ map1, bf16t* __restrict__ map2) {
  const int inp = blockIdx.y;
  const bf16t* __restrict__ E = inp ? enc2 : enc1;
  const float* __restrict__ Dm = inp ? d2 : d1;
  bf16t* __restrict__ O = inp ? map2 : map1;
  const int t0 = blockIdx.x * 16;
  const int j = threadIdx.x;
  if (j >= 100) return;
  float acc[16];
#pragma unroll
  for (int r = 0; r < 16; ++r) acc[r] = 0.f;
  for (int k2 = 0; k2 < 50; ++k2) {
    const int k0 = 2 * k2, k1 = k0 + 1;
    float wE0 = W[k0 * 100 + j], wE1 = W[k1 * 100 + j];
    float wD0 = W[(100 + k0) * 100 + j], wD1 = W[(100 + k1) * 100 + j];
    float wP0 = W[(200 + k0) * 100 + j], wP1 = W[(200 + k1) * 100 + j];
    float wM0 = W[(300 + k0) * 100 + j], wM1 = W[(300 + k1) * 100 + j];
    float t10 = wE0 + wM0, t11 = wE1 + wM1;
    float t20 = wD0 - wM0, t21 = wD1 - wM1;
#pragma unroll
    for (int r = 0; r < 16; ++r) {
      float2 e = ldpair(E + (size_t)(t0 + r) * 100 + k0);
      float2 dv = ldpair(Dm + (size_t)(t0 + r) * 100 + k0);
      float a = acc[r];
      a = fmaf(e.x, t10, a);
      a = fmaf(dv.x, t20, a);
      a = fmaf(e.x * dv.x, wP0, a);
      a = fmaf(e.y, t11, a);
      a = fmaf(dv.y, t21, a);
      a = fmaf(e.y * dv.y, wP1, a);
      acc[r] = a;
    }
  }
  float bj = bias[j];
#pragma unroll
  for (int r = 0; r < 16; ++r)
    O[(size_t)(t0 + r) * 100 + j] = f2bf(fmaxf(acc[r] + bj, 0.f));
}

// ---------------- masked pooling ----------------
__global__ __launch_bounds__(128) void pool_kernel(
    const bf16t* __restrict__ cmp1, const bf16t* __restrict__ cmp2,
    const float* __restrict__ m1, const float* __restrict__ m2,
    float* __restrict__ pooled) {
  int b = blockIdx.x & 127, inp = blockIdx.x >> 7;
  const bf16t* C = (inp ? cmp2 : cmp1) + (size_t)b * SQ * 100;
  const float* M = (inp ? m2 : m1) + b * SQ;
  int f = threadIdx.x;
  float ms = 0.f;
  for (int s = f; s < SQ; s += 128) ms += M[s];
  __shared__ float red[128];
  red[f] = ms;
  __syncthreads();
  for (int o = 64; o > 0; o >>= 1) {
    if (f < o) red[f] += red[f + o];
    __syncthreads();
  }
  float msum = red[0];
  if (f < 100) {
    float sm = 0.f, mx = -1e30f;
    for (int s = 0; s < SQ; ++s) {
      float v = bf2f(C[(size_t)s * 100 + f]) * M[s];
      sm += v;
      mx = fmaxf(mx, v);
    }
    pooled[b * 400 + inp * 200 + f] = sm / msum;
    pooled[b * 400 + inp * 200 + 100 + f] = mx;
  }
}

// ---------------- final MLP + softmax ----------------
__global__ __launch_bounds__(128) void final_kernel(
    const float* __restrict__ pooled, const float* __restrict__ W1,
    const float* __restrict__ b1, const float* __restrict__ W2,
    const float* __restrict__ b2, float* __restrict__ out) {
  int b = blockIdx.x;
  int j = threadIdx.x;
  __shared__ float pr[400];
  __shared__ float h[100];
  for (int idx = j; idx < 400; idx += 128) pr[idx] = pooled[b * 400 + idx];
  __syncthreads();
  if (j < 100) {
    float a = b1[j];
    for (int k = 0; k < 400; ++k) a += pr[k] * W1[k * 100 + j];
    h[j] = tanhx(a);
  }
  __syncthreads();
  if (j == 0) {
    float l0 = b2[0], l1 = b2[1];
    for (int k = 0; k < 100; ++k) {
      l0 += h[k] * W2[k * 2];
      l1 += h[k] * W2[k * 2 + 1];
    }
    float mx = fmaxf(l0, l1);
    float e0 = __expf(l0 - mx), e1 = __expf(l1 - mx);
    float inv = 1.f / (e0 + e1);
    out[b * 2] = e0 * inv;
    out[b * 2 + 1] = e1 * inv;
  }
}

extern "C" void kernel_launch(void* const* d_in, const int* in_sizes, int n_in,
                              void* d_out, int out_size, void* d_ws, size_t ws_size,
                              hipStream_t stream) {
  const int* x1 = (const int*)d_in[0];
  const int* x2 = (const int*)d_in[1];
  const float* emb = (const float*)d_in[2];
  const float* b1f_Wx = (const float*)d_in[3];
  const float* b1f_Wh = (const float*)d_in[4];
  const float* b1f_b = (const float*)d_in[5];
  const float* b1b_Wx = (const float*)d_in[6];
  const float* b1b_Wh = (const float*)d_in[7];
  const float* b1b_b = (const float*)d_in[8];
  const float* dense_W = (const float*)d_in[9];
  const float* dense_b = (const float*)d_in[10];
  const float* b2f_Wx = (const float*)d_in[11];
  const float* b2f_Wh = (const float*)d_in[12];
  const float* b2f_b = (const float*)d_in[13];
  const float* b2b_Wx = (const float*)d_in[14];
  const float* b2b_Wh = (const float*)d_in[15];
  const float* b2b_b = (const float*)d_in[16];
  const float* dense1_W = (const float*)d_in[17];
  const float* dense1_b = (const float*)d_in[18];
  const float* out_W = (const float*)d_in[19];
  const float* out_b = (const float*)d_in[20];
  float* out = (float*)d_out;

  // ---- workspace layout (~151 MB total) ----
  // region R0: xz  [4][TOKN][200] bf16 = 104.86 MB; d1/d2 (fp32, 52.4 MB) alias it
  //   (xz live gemm->scan; d live attn->dense; disjoint lifetimes)
  // region R1: enc1/enc2 [TOKN][100] bf16 each; e1/e2 (fp32 TOKN*50) alias
  //   (e live embed->gemm1; enc written by lstm1 afterwards)
  // region R2: map1/map2 [TOKN][100] bf16 each
  char* base = (char*)d_ws;
  bf16t* xz = (bf16t*)base;
  float* d1 = (float*)base;
  float* d2 = d1 + (size_t)TOKN * 100;
  char* r1 = base + (size_t)4 * TOKN * 200 * sizeof(bf16t);
  bf16t* enc1 = (bf16t*)r1;
  bf16t* enc2 = enc1 + (size_t)TOKN * 100;
  float* e1 = (float*)r1;
  float* e2 = e1 + (size_t)TOKN * 50;
  bf16t* map1 = enc2 + (size_t)TOKN * 100;
  bf16t* map2 = map1 + (size_t)TOKN * 100;
  float* m1 = (float*)(map2 + (size_t)TOKN * 100);
  float* m2 = m1 + TOKN;
  float* pooled = m2 + TOKN;
  bf16t* cmp1 = enc1;  // alias: enc dead after dense
  bf16t* cmp2 = enc2;
  (void)in_sizes; (void)n_in; (void)out_size; (void)ws_size;

  embed_kernel<<<dim3((TOKN * 50 + 255) / 256, 2), 256, 0, stream>>>(
      x1, x2, emb, e1, e2, m1, m2);
  xz_gemm<50, float><<<dim3(TOKN / 16, 4), 256, 0, stream>>>(
      e1, e2, b1f_Wx, b1f_b, b1b_Wx, b1b_b, xz);
  lstm_scan<<<512, 256, 0, stream>>>(xz, b1f_Wh, b1b_Wh, enc1, enc2, m1, m2, 1);
  attn_kernel<<<SQ, 256, 0, stream>>>(enc1, enc2, m1, m2, d1, d2);
  dense_kernel<<<dim3(TOKN / 16, 2), 128, 0, stream>>>(
      enc1, enc2, d1, d2, dense_W, dense_b, map1, map2);
  xz_gemm<100, bf16t><<<dim3(TOKN / 16, 4), 256, 0, stream>>>(
      map1, map2, b2f_Wx, b2f_b, b2b_Wx, b2b_b, xz);
  lstm_scan<<<512, 256, 0, stream>>>(xz, b2f_Wh, b2b_Wh, cmp1, cmp2, m1, m2, 0);
  pool_kernel<<<256, 128, 0, stream>>>(cmp1, cmp2, m1, m2, pooled);
  final_kernel<<<128, 128, 0, stream>>>(pooled, dense1_W, dense1_b, out_W, out_b, out);
}

// Round 4
// 1323.264 us; speedup vs baseline: 1.8205x; 1.3661x over previous
//
#include <hip/hip_runtime.h>

#define TOKN 65536   // 128*512
#define SQ 512
#define BB 128
#define DD 100
#define APAD 132

typedef unsigned short bf16t;
typedef __attribute__((ext_vector_type(8))) short bf16x8;
typedef __attribute__((ext_vector_type(4))) float floatx4;

__device__ __forceinline__ float bf2f(bf16t v) {
  unsigned u = ((unsigned)v) << 16;
  return __uint_as_float(u);
}
__device__ __forceinline__ bf16t f2bf(float x) {
  unsigned u = __float_as_uint(x);
  unsigned r = u + 0x7FFFu + ((u >> 16) & 1u);
  return (bf16t)(r >> 16);
}
__device__ __forceinline__ float2 ldpair(const float* p) { return *(const float2*)p; }
__device__ __forceinline__ float2 ldpair(const bf16t* p) {
  unsigned u = *(const unsigned*)p;
  float2 r;
  r.x = __uint_as_float(u << 16);
  r.y = __uint_as_float(u & 0xFFFF0000u);
  return r;
}

__device__ __forceinline__ float sigm(float x) { return 1.f / (1.f + __expf(-x)); }
__device__ __forceinline__ float tanhx(float x) { return 1.f - 2.f / (1.f + __expf(2.f * x)); }

// ---------------- embedding + mask: e[TOKN][64] bf16 (K-padded) ----------------
__global__ __launch_bounds__(256) void embed_kernel(
    const int* __restrict__ x1, const int* __restrict__ x2,
    const float* __restrict__ emb,
    bf16t* __restrict__ e1, bf16t* __restrict__ e2,
    float* __restrict__ m1, float* __restrict__ m2) {
  const int which = blockIdx.y;
  const int* __restrict__ x = which ? x2 : x1;
  bf16t* __restrict__ e = which ? e2 : e1;
  float* __restrict__ m = which ? m2 : m1;
  int idx = blockIdx.x * 256 + threadIdx.x;  // over TOKN*64
  int t = idx >> 6, d = idx & 63;
  int tok = x[t];
  float mk = (tok != 0) ? 1.f : 0.f;
  float v = (d < 50) ? emb[tok * 50 + d] * mk : 0.f;
  e[idx] = f2bf(v);
  if (d == 0) m[t] = mk;
}

// ---------------- weight prep: transpose+pad+fold to bf16 ----------------
// sec0: w1T[2][208][64]   from b1{f,b}_Wx [50][200]
// sec1: w2T[2][208][128]  from b2{f,b}_Wx [100][200]
// sec2: wdT[128][384]     from dense_W [400][100], folded [wE+wM, wD-wM, wP]
__global__ __launch_bounds__(256) void wprep_kernel(
    const float* __restrict__ w1f, const float* __restrict__ w1b,
    const float* __restrict__ w2f, const float* __restrict__ w2b,
    const float* __restrict__ dW,
    bf16t* __restrict__ w1T, bf16t* __restrict__ w2T, bf16t* __restrict__ wdT) {
  int idx = blockIdx.x * 256 + threadIdx.x;
  int sec = blockIdx.y;
  if (sec == 0) {
    if (idx >= 2 * 208 * 64) return;
    int d = idx / (208 * 64), r = idx % (208 * 64);
    int n = r >> 6, k = r & 63;
    const float* W = d ? w1b : w1f;
    float v = (n < 200 && k < 50) ? W[k * 200 + n] : 0.f;
    w1T[idx] = f2bf(v);
  } else if (sec == 1) {
    if (idx >= 2 * 208 * 128) return;
    int d = idx / (208 * 128), r = idx % (208 * 128);
    int n = r >> 7, k = r & 127;
    const float* W = d ? w2b : w2f;
    float v = (n < 200 && k < 100) ? W[k * 200 + n] : 0.f;
    w2T[idx] = f2bf(v);
  } else {
    if (idx >= 128 * 384) return;
    int n = idx / 384, kv = idx % 384;
    int reg = kv >> 7, kk = kv & 127;
    float v = 0.f;
    if (n < 100 && kk < 100) {
      if (reg == 0) v = dW[kk * 100 + n] + dW[(300 + kk) * 100 + n];
      else if (reg == 1) v = dW[(100 + kk) * 100 + n] - dW[(300 + kk) * 100 + n];
      else v = dW[(200 + kk) * 100 + n];
    }
    wdT[idx] = f2bf(v);
  }
}

// ---------------- MFMA xz GEMM: out[combo][t][200] = A@Wx + b ----------------
// A [TOKN][KP] bf16; WT [2][208][KP] bf16 (n-major).  Wave = 16 rows x 13 n-tiles.
template <int KP>
__global__ __launch_bounds__(256) void xz_mfma(
    const bf16t* __restrict__ A1, const bf16t* __restrict__ A2,
    const bf16t* __restrict__ WT,
    const float* __restrict__ bf_, const float* __restrict__ bb_,
    bf16t* __restrict__ out) {
  const int combo = blockIdx.y;
  const bf16t* __restrict__ A = (combo < 2) ? A1 : A2;
  const bf16t* __restrict__ W = WT + (size_t)(combo & 1) * 208 * KP;
  const float* __restrict__ bias = (combo & 1) ? bb_ : bf_;
  bf16t* __restrict__ O = out + (size_t)combo * TOKN * 200;
  const int tid = threadIdx.x;
  const int wave = tid >> 6, lane = tid & 63;
  const int m0 = blockIdx.x * 64 + wave * 16;
  const int l15 = lane & 15, quad = lane >> 4;
  floatx4 acc[13];
#pragma unroll
  for (int nt = 0; nt < 13; ++nt) acc[nt] = (floatx4){0.f, 0.f, 0.f, 0.f};
  const bf16t* __restrict__ arow = A + (size_t)(m0 + l15) * KP + quad * 8;
  const bf16t* __restrict__ wb = W + (size_t)l15 * KP + quad * 8;
#pragma unroll
  for (int ks = 0; ks < KP / 32; ++ks) {
    bf16x8 a = *(const bf16x8*)(arow + ks * 32);
#pragma unroll
    for (int nt = 0; nt < 13; ++nt) {
      bf16x8 b = *(const bf16x8*)(wb + (size_t)nt * 16 * KP + ks * 32);
      acc[nt] = __builtin_amdgcn_mfma_f32_16x16x32_bf16(a, b, acc[nt], 0, 0, 0);
    }
  }
  const int crow = m0 + quad * 4;
#pragma unroll
  for (int nt = 0; nt < 13; ++nt) {
    int n = nt * 16 + l15;
    if (n < 200) {
      float bn = bias[n];
#pragma unroll
      for (int r = 0; r < 4; ++r)
        O[(size_t)(crow + r) * 200 + n] = f2bf(acc[nt][r] + bn);
    }
  }
}

// ---------------- MFMA dense: map = relu([e,d,e*d]@W' + b), out [t][128] ----------------
__global__ __launch_bounds__(256) void dense_mfma(
    const bf16t* __restrict__ enc1, const bf16t* __restrict__ enc2,
    const bf16t* __restrict__ d1b, const bf16t* __restrict__ d2b,
    const bf16t* __restrict__ wdT, const float* __restrict__ bias,
    bf16t* __restrict__ map1, bf16t* __restrict__ map2) {
  const int inp = blockIdx.y;
  const bf16t* __restrict__ E = inp ? enc2 : enc1;
  const bf16t* __restrict__ Db = inp ? d2b : d1b;
  bf16t* __restrict__ O = inp ? map2 : map1;
  const int tid = threadIdx.x;
  const int wave = tid >> 6, lane = tid & 63;
  const int m0 = blockIdx.x * 64 + wave * 16;
  const int l15 = lane & 15, quad = lane >> 4;
  floatx4 acc[8];
#pragma unroll
  for (int nt = 0; nt < 8; ++nt) acc[nt] = (floatx4){0.f, 0.f, 0.f, 0.f};
  const bf16t* __restrict__ erow = E + (size_t)(m0 + l15) * 128 + quad * 8;
  const bf16t* __restrict__ drow = Db + (size_t)(m0 + l15) * 128 + quad * 8;
  const bf16t* __restrict__ wb = wdT + (size_t)l15 * 384 + quad * 8;
#pragma unroll
  for (int ks = 0; ks < 4; ++ks) {
    bf16x8 ae = *(const bf16x8*)(erow + ks * 32);
    bf16x8 ad = *(const bf16x8*)(drow + ks * 32);
    bf16x8 aed;
#pragma unroll
    for (int q = 0; q < 8; ++q) {
      float pe = bf2f((bf16t)ae[q]);
      float pd = bf2f((bf16t)ad[q]);
      aed[q] = (short)f2bf(pe * pd);
    }
#pragma unroll
    for (int nt = 0; nt < 8; ++nt) {
      const bf16t* wn = wb + (size_t)nt * 16 * 384 + ks * 32;
      bf16x8 b0 = *(const bf16x8*)(wn);
      acc[nt] = __builtin_amdgcn_mfma_f32_16x16x32_bf16(ae, b0, acc[nt], 0, 0, 0);
      bf16x8 b1 = *(const bf16x8*)(wn + 128);
      acc[nt] = __builtin_amdgcn_mfma_f32_16x16x32_bf16(ad, b1, acc[nt], 0, 0, 0);
      bf16x8 b2 = *(const bf16x8*)(wn + 256);
      acc[nt] = __builtin_amdgcn_mfma_f32_16x16x32_bf16(aed, b2, acc[nt], 0, 0, 0);
    }
  }
  const int crow = m0 + quad * 4;
#pragma unroll
  for (int nt = 0; nt < 8; ++nt) {
    int n = nt * 16 + l15;
    float bn = (n < 100) ? bias[n] : 0.f;
#pragma unroll
    for (int r = 0; r < 4; ++r) {
      float v = (n < 100) ? fmaxf(acc[nt][r] + bn, 0.f) : 0.f;
      O[(size_t)(crow + r) * 128 + n] = f2bf(v);
    }
  }
}

// ---------------- LSTM scan: one block per (scan, batch); enc stride 128 ----------------
__global__ __launch_bounds__(256) void lstm_scan(
    const bf16t* __restrict__ xz,
    const float* __restrict__ Whf, const float* __restrict__ Whb,
    bf16t* __restrict__ out1, bf16t* __restrict__ out2,
    const float* __restrict__ m1, const float* __restrict__ m2,
    int hasMask) {
  const int blk = blockIdx.x;
  const int scan = blk >> 7;
  const int b = blk & 127;
  const int inp = scan >> 1;
  const int dir = scan & 1;
  const float* __restrict__ Wh = dir ? Whb : Whf;
  const bf16t* __restrict__ xzs = xz + (size_t)scan * TOKN * 200 + (size_t)b * SQ * 200;
  bf16t* __restrict__ outp = (inp ? out2 : out1) + (size_t)b * SQ * 128 + dir * 50;
  const float* __restrict__ mk = (inp ? m2 : m1) + b * SQ;

  const int j = threadIdx.x;
  __shared__ __align__(16) float h_lds[52];
  __shared__ float act[200];
  float whc[50];
  if (j < 200) {
#pragma unroll
    for (int k = 0; k < 50; ++k) whc[k] = Wh[k * 200 + j];
  }
  if (j < 52) h_lds[j] = 0.f;
  float c = 0.f;
  float z0 = 0.f, z1 = 0.f;
  if (j < 200) {
    z0 = bf2f(xzs[(size_t)(dir ? (SQ - 1) : 0) * 200 + j]);
    z1 = bf2f(xzs[(size_t)(dir ? (SQ - 2) : 1) * 200 + j]);
  }
  __syncthreads();
  for (int t = 0; t < SQ; ++t) {
    int tp = (t + 2 < SQ) ? (t + 2) : (SQ - 1);
    int rowp = dir ? (SQ - 1 - tp) : tp;
    float znext = 0.f;
    if (j < 200) {
      znext = bf2f(xzs[(size_t)rowp * 200 + j]);
      float za = z0, zb = 0.f, zc = 0.f, zd = 0.f;
#pragma unroll
      for (int k = 0; k < 48; k += 4) {
        za = fmaf(h_lds[k], whc[k], za);
        zb = fmaf(h_lds[k + 1], whc[k + 1], zb);
        zc = fmaf(h_lds[k + 2], whc[k + 2], zc);
        zd = fmaf(h_lds[k + 3], whc[k + 3], zd);
      }
      za = fmaf(h_lds[48], whc[48], za);
      zb = fmaf(h_lds[49], whc[49], zb);
      float z = (za + zb) + (zc + zd);
      float a = (j >= 100 && j < 150) ? tanhx(z) : sigm(z);
      act[j] = a;
    }
    __syncthreads();
    if (j < 50) {
      c = act[50 + j] * c + act[j] * act[100 + j];
      float hn = act[150 + j] * tanhx(c);
      h_lds[j] = hn;
      float mv = hasMask ? mk[t] : 1.f;
      outp[(size_t)t * 128 + j] = f2bf(hn * mv);
    } else if (dir == 0 && j < 64) {
      // zero the K-pad columns 100..127 (once; dir0 block owns them)
      *(unsigned*)&outp[(size_t)t * 128 + 100 + 2 * (j - 50)] = 0u;
    }
    __syncthreads();
    z0 = z1;
    z1 = znext;
  }
}

// ---------------- attention (per timestep s) ----------------
__global__ __launch_bounds__(256) void attn_kernel(
    const bf16t* __restrict__ enc1, const bf16t* __restrict__ enc2,
    const float* __restrict__ m1, const float* __restrict__ m2,
    bf16t* __restrict__ d1b, bf16t* __restrict__ d2b) {
  const int s = blockIdx.x;
  const int tid = threadIdx.x;
  __shared__ __align__(16) float E1[BB][DD];
  __shared__ __align__(16) float E2[BB + 1][DD];
  __shared__ __align__(16) float Ah[64][APAD];
  __shared__ float mk1[BB], mk2[BB];
  __shared__ float rden[64];

  for (int idx = tid; idx < BB * 50; idx += 256) {
    int i = idx / 50, dp = idx - i * 50;
    float2 v1 = ldpair(enc1 + ((size_t)i * SQ + s) * 128 + 2 * dp);
    E1[i][2 * dp] = v1.x;
    E1[i][2 * dp + 1] = v1.y;
    float2 v2 = ldpair(enc2 + ((size_t)i * SQ + s) * 128 + 2 * dp);
    E2[i][2 * dp] = v2.x;
    E2[i][2 * dp + 1] = v2.y;
  }
  if (tid < BB) {
    mk1[tid] = m1[tid * SQ + s];
    mk2[tid] = m2[tid * SQ + s];
  }
  __syncthreads();

  const int ti = tid >> 4, tjj = tid & 15;
  const int xj = tid & 127;
  const int xd0 = (tid >> 7) * 50;
  float N[50];
#pragma unroll
  for (int q = 0; q < 50; ++q) N[q] = 0.f;
  float Dacc = 0.f, M = -1e30f;

  for (int half = 0; half < 2; ++half) {
    const int r0 = half * 64;
    float acc[4][8];
#pragma unroll
    for (int ii = 0; ii < 4; ++ii)
#pragma unroll
      for (int jj = 0; jj < 8; ++jj) acc[ii][jj] = 0.f;
    for (int k = 0; k < DD; k += 4) {
      float4 a4[4], b4[8];
#pragma unroll
      for (int ii = 0; ii < 4; ++ii)
        a4[ii] = *(const float4*)&E1[r0 + 4 * ti + ii][k];
#pragma unroll
      for (int jj = 0; jj < 8; ++jj)
        b4[jj] = *(const float4*)&E2[tjj + 16 * jj][k];
#pragma unroll
      for (int ii = 0; ii < 4; ++ii)
#pragma unroll
        for (int jj = 0; jj < 8; ++jj)
          acc[ii][jj] += a4[ii].x * b4[jj].x + a4[ii].y * b4[jj].y +
                         a4[ii].z * b4[jj].z + a4[ii].w * b4[jj].w;
    }
#pragma unroll
    for (int ii = 0; ii < 4; ++ii)
#pragma unroll
      for (int jj = 0; jj < 8; ++jj)
        Ah[4 * ti + ii][tjj + 16 * jj] = acc[ii][jj];
    __syncthreads();

    {
      float lm = M;
      for (int i = 0; i < 64; ++i) lm = fmaxf(lm, Ah[i][xj]);
      float scale = __expf(M - lm);
      Dacc *= scale;
#pragma unroll
      for (int q = 0; q < 50; ++q) N[q] *= scale;
      for (int i = 0; i < 64; ++i) {
        float p = __expf(Ah[i][xj] - lm) * mk1[r0 + i];
        Dacc += p;
        const float2* e1p = (const float2*)&E1[r0 + i][xd0];
#pragma unroll
        for (int q = 0; q < 25; ++q) {
          float2 ev = e1p[q];
          N[2 * q] += p * ev.x;
          N[2 * q + 1] += p * ev.y;
        }
      }
      M = lm;
    }
    __syncthreads();

    {
      int row = tid >> 2, seg = tid & 3;
      float mx = -1e30f;
      for (int q = 0; q < 32; ++q) mx = fmaxf(mx, Ah[row][seg + 4 * q]);
      mx = fmaxf(mx, __shfl_xor(mx, 1));
      mx = fmaxf(mx, __shfl_xor(mx, 2));
      float sm = 0.f;
      for (int q = 0; q < 32; ++q) {
        int jc = seg + 4 * q;
        float p = __expf(Ah[row][jc] - mx) * mk2[jc];
        Ah[row][jc] = p;
        sm += p;
      }
      sm += __shfl_xor(sm, 1);
      sm += __shfl_xor(sm, 2);
      if (seg == 0) rden[row] = sm + 1e-8f;
    }
    __syncthreads();

    {
      float o[4][8];
#pragma unroll
      for (int ii = 0; ii < 4; ++ii)
#pragma unroll
        for (int jj = 0; jj < 8; ++jj) o[ii][jj] = 0.f;
      for (int jb = 0; jb < BB; ++jb) {
        float pv[4], ev[8];
#pragma unroll
        for (int ii = 0; ii < 4; ++ii) pv[ii] = Ah[4 * ti + ii][jb];
#pragma unroll
        for (int jj = 0; jj < 8; ++jj) ev[jj] = E2[jb][tjj + 16 * jj];
#pragma unroll
        for (int ii = 0; ii < 4; ++ii)
#pragma unroll
          for (int jj = 0; jj < 8; ++jj) o[ii][jj] += pv[ii] * ev[jj];
      }
#pragma unroll
      for (int ii = 0; ii < 4; ++ii) {
        int i = r0 + 4 * ti + ii;
        float inv = 1.f / rden[4 * ti + ii];
#pragma unroll
        for (int jj = 0; jj < 8; ++jj) {
          int d = tjj + 16 * jj;
          float val = (d < DD) ? o[ii][jj] * inv : 0.f;
          d1b[((size_t)i * SQ + s) * 128 + d] = f2bf(val);
        }
      }
    }
    __syncthreads();
  }
  float invD = 1.f / (Dacc + 1e-8f);
#pragma unroll
  for (int q = 0; q < 50; ++q)
    d2b[((size_t)xj * SQ + s) * 128 + xd0 + q] = f2bf(N[q] * invD);
  if (xd0 == 50) {
#pragma unroll
    for (int q = 0; q < 28; ++q)
      d2b[((size_t)xj * SQ + s) * 128 + 100 + q] = 0;
  }
}

// ---------------- masked pooling (cmp stride 128) ----------------
__global__ __launch_bounds__(128) void pool_kernel(
    const bf16t* __restrict__ cmp1, const bf16t* __restrict__ cmp2,
    const float* __restrict__ m1, const float* __restrict__ m2,
    float* __restrict__ pooled) {
  int b = blockIdx.x & 127, inp = blockIdx.x >> 7;
  const bf16t* C = (inp ? cmp2 : cmp1) + (size_t)b * SQ * 128;
  const float* M = (inp ? m2 : m1) + b * SQ;
  int f = threadIdx.x;
  float ms = 0.f;
  for (int s = f; s < SQ; s += 128) ms += M[s];
  __shared__ float red[128];
  red[f] = ms;
  __syncthreads();
  for (int o = 64; o > 0; o >>= 1) {
    if (f < o) red[f] += red[f + o];
    __syncthreads();
  }
  float msum = red[0];
  if (f < 100) {
    float sm = 0.f, mx = -1e30f;
    for (int s = 0; s < SQ; ++s) {
      float v = bf2f(C[(size_t)s * 128 + f]) * M[s];
      sm += v;
      mx = fmaxf(mx, v);
    }
    pooled[b * 400 + inp * 200 + f] = sm / msum;
    pooled[b * 400 + inp * 200 + 100 + f] = mx;
  }
}

// ---------------- final MLP + softmax ----------------
__global__ __launch_bounds__(128) void final_kernel(
    const float* __restrict__ pooled, const float* __restrict__ W1,
    const float* __restrict__ b1, const float* __restrict__ W2,
    const float* __restrict__ b2, float* __restrict__ out) {
  int b = blockIdx.x;
  int j = threadIdx.x;
  __shared__ float pr[400];
  __shared__ float h[100];
  for (int idx = j; idx < 400; idx += 128) pr[idx] = pooled[b * 400 + idx];
  __syncthreads();
  if (j < 100) {
    float a = b1[j];
    for (int k = 0; k < 400; ++k) a += pr[k] * W1[k * 100 + j];
    h[j] = tanhx(a);
  }
  __syncthreads();
  if (j == 0) {
    float l0 = b2[0], l1 = b2[1];
    for (int k = 0; k < 100; ++k) {
      l0 += h[k] * W2[k * 2];
      l1 += h[k] * W2[k * 2 + 1];
    }
    float mx = fmaxf(l0, l1);
    float e0 = __expf(l0 - mx), e1 = __expf(l1 - mx);
    float inv = 1.f / (e0 + e1);
    out[b * 2] = e0 * inv;
    out[b * 2 + 1] = e1 * inv;
  }
}

extern "C" void kernel_launch(void* const* d_in, const int* in_sizes, int n_in,
                              void* d_out, int out_size, void* d_ws, size_t ws_size,
                              hipStream_t stream) {
  const int* x1 = (const int*)d_in[0];
  const int* x2 = (const int*)d_in[1];
  const float* emb = (const float*)d_in[2];
  const float* b1f_Wx = (const float*)d_in[3];
  const float* b1f_Wh = (const float*)d_in[4];
  const float* b1f_b = (const float*)d_in[5];
  const float* b1b_Wx = (const float*)d_in[6];
  const float* b1b_Wh = (const float*)d_in[7];
  const float* b1b_b = (const float*)d_in[8];
  const float* dense_W = (const float*)d_in[9];
  const float* dense_b = (const float*)d_in[10];
  const float* b2f_Wx = (const float*)d_in[11];
  const float* b2f_Wh = (const float*)d_in[12];
  const float* b2f_b = (const float*)d_in[13];
  const float* b2b_Wx = (const float*)d_in[14];
  const float* b2b_Wh = (const float*)d_in[15];
  const float* b2b_b = (const float*)d_in[16];
  const float* dense1_W = (const float*)d_in[17];
  const float* dense1_b = (const float*)d_in[18];
  const float* out_W = (const float*)d_in[19];
  const float* out_b = (const float*)d_in[20];
  float* out = (float*)d_out;

  // ---- workspace layout (~173 MB) ----
  // R0 (104.9 MB): xz [4][TOKN][200] bf16  (live gemm->scan)
  //                d1b/d2b [TOKN][128] bf16 alias (live attn->dense)
  // R1 (33.5 MB):  enc1/enc2 [TOKN][128] bf16; e1b/e2b [TOKN][64] alias;
  //                cmp1/cmp2 alias (scan2 output)
  // R2 (33.5 MB):  map1/map2 [TOKN][128] bf16
  // R3: masks + pooled + prepped weights
  char* base = (char*)d_ws;
  bf16t* xz = (bf16t*)base;
  bf16t* d1b = (bf16t*)base;
  bf16t* d2b = d1b + (size_t)TOKN * 128;
  char* r1 = base + (size_t)4 * TOKN * 200 * 2;
  bf16t* enc1 = (bf16t*)r1;
  bf16t* enc2 = enc1 + (size_t)TOKN * 128;
  bf16t* e1b = (bf16t*)r1;
  bf16t* e2b = e1b + (size_t)TOKN * 64;
  char* r2 = r1 + (size_t)2 * TOKN * 128 * 2;
  bf16t* map1 = (bf16t*)r2;
  bf16t* map2 = map1 + (size_t)TOKN * 128;
  char* r3 = r2 + (size_t)2 * TOKN * 128 * 2;
  float* m1 = (float*)r3;
  float* m2 = m1 + TOKN;
  float* pooled = m2 + TOKN;
  bf16t* w1T = (bf16t*)(r3 + ((size_t)2 * TOKN + 128 * 400) * 4);
  bf16t* w2T = w1T + 2 * 208 * 64;
  bf16t* wdT = w2T + 2 * 208 * 128;
  bf16t* cmp1 = enc1;
  bf16t* cmp2 = enc2;
  (void)in_sizes; (void)n_in; (void)out_size; (void)ws_size;

  embed_kernel<<<dim3(TOKN * 64 / 256, 2), 256, 0, stream>>>(
      x1, x2, emb, e1b, e2b, m1, m2);
  wprep_kernel<<<dim3(208, 3), 256, 0, stream>>>(
      b1f_Wx, b1b_Wx, b2f_Wx, b2b_Wx, dense_W, w1T, w2T, wdT);
  xz_mfma<64><<<dim3(TOKN / 64, 4), 256, 0, stream>>>(
      e1b, e2b, w1T, b1f_b, b1b_b, xz);
  lstm_scan<<<512, 256, 0, stream>>>(xz, b1f_Wh, b1b_Wh, enc1, enc2, m1, m2, 1);
  attn_kernel<<<SQ, 256, 0, stream>>>(enc1, enc2, m1, m2, d1b, d2b);
  dense_mfma<<<dim3(TOKN / 64, 2), 256, 0, stream>>>(
      enc1, enc2, d1b, d2b, wdT, dense_b, map1, map2);
  xz_mfma<128><<<dim3(TOKN / 64, 4), 256, 0, stream>>>(
      map1, map2, w2T, b2f_b, b2b_b, xz);
  lstm_scan<<<512, 256, 0, stream>>>(xz, b2f_Wh, b2b_Wh, cmp1, cmp2, m1, m2, 0);
  pool_kernel<<<256, 128, 0, stream>>>(cmp1, cmp2, m1, m2, pooled);
  final_kernel<<<128, 128, 0, stream>>>(pooled, dense1_W, dense1_b, out_W, out_b, out);
}

// Round 5
// 1248.279 us; speedup vs baseline: 1.9299x; 1.0601x over previous
//
#include <hip/hip_runtime.h>

#define TOKN 65536   // 128*512
#define SQ 512
#define BB 128
#define DD 100
#define APAD 132

typedef unsigned short bf16t;
typedef __attribute__((ext_vector_type(8))) short bf16x8;
typedef __attribute__((ext_vector_type(4))) float floatx4;

__device__ __forceinline__ float bf2f(bf16t v) {
  unsigned u = ((unsigned)v) << 16;
  return __uint_as_float(u);
}
__device__ __forceinline__ bf16t f2bf(float x) {
  unsigned u = __float_as_uint(x);
  unsigned r = u + 0x7FFFu + ((u >> 16) & 1u);
  return (bf16t)(r >> 16);
}
__device__ __forceinline__ float2 ldpair(const float* p) { return *(const float2*)p; }
__device__ __forceinline__ float2 ldpair(const bf16t* p) {
  unsigned u = *(const unsigned*)p;
  float2 r;
  r.x = __uint_as_float(u << 16);
  r.y = __uint_as_float(u & 0xFFFF0000u);
  return r;
}

__device__ __forceinline__ float sigm(float x) { return 1.f / (1.f + __expf(-x)); }
__device__ __forceinline__ float tanhx(float x) { return 1.f - 2.f / (1.f + __expf(2.f * x)); }

// ---------------- embedding + mask: e[TOKN][64] bf16 (K-padded) ----------------
__global__ __launch_bounds__(256) void embed_kernel(
    const int* __restrict__ x1, const int* __restrict__ x2,
    const float* __restrict__ emb,
    bf16t* __restrict__ e1, bf16t* __restrict__ e2,
    float* __restrict__ m1, float* __restrict__ m2) {
  const int which = blockIdx.y;
  const int* __restrict__ x = which ? x2 : x1;
  bf16t* __restrict__ e = which ? e2 : e1;
  float* __restrict__ m = which ? m2 : m1;
  int idx = blockIdx.x * 256 + threadIdx.x;  // over TOKN*64
  int t = idx >> 6, d = idx & 63;
  int tok = x[t];
  float mk = (tok != 0) ? 1.f : 0.f;
  float v = (d < 50) ? emb[tok * 50 + d] * mk : 0.f;
  e[idx] = f2bf(v);
  if (d == 0) m[t] = mk;
}

// ---------------- weight prep: transpose+pad+fold to bf16 ----------------
// sec0: w1T[2][208][64]   from b1{f,b}_Wx [50][200]
// sec1: w2T[2][208][128]  from b2{f,b}_Wx [100][200]
// sec2: wdT[128][384]     from dense_W [400][100], folded [wE+wM, wD-wM, wP]
__global__ __launch_bounds__(256) void wprep_kernel(
    const float* __restrict__ w1f, const float* __restrict__ w1b,
    const float* __restrict__ w2f, const float* __restrict__ w2b,
    const float* __restrict__ dW,
    bf16t* __restrict__ w1T, bf16t* __restrict__ w2T, bf16t* __restrict__ wdT) {
  int idx = blockIdx.x * 256 + threadIdx.x;
  int sec = blockIdx.y;
  if (sec == 0) {
    if (idx >= 2 * 208 * 64) return;
    int d = idx / (208 * 64), r = idx % (208 * 64);
    int n = r >> 6, k = r & 63;
    const float* W = d ? w1b : w1f;
    float v = (n < 200 && k < 50) ? W[k * 200 + n] : 0.f;
    w1T[idx] = f2bf(v);
  } else if (sec == 1) {
    if (idx >= 2 * 208 * 128) return;
    int d = idx / (208 * 128), r = idx % (208 * 128);
    int n = r >> 7, k = r & 127;
    const float* W = d ? w2b : w2f;
    float v = (n < 200 && k < 100) ? W[k * 200 + n] : 0.f;
    w2T[idx] = f2bf(v);
  } else {
    if (idx >= 128 * 384) return;
    int n = idx / 384, kv = idx % 384;
    int reg = kv >> 7, kk = kv & 127;
    float v = 0.f;
    if (n < 100 && kk < 100) {
      if (reg == 0) v = dW[kk * 100 + n] + dW[(300 + kk) * 100 + n];
      else if (reg == 1) v = dW[(100 + kk) * 100 + n] - dW[(300 + kk) * 100 + n];
      else v = dW[(200 + kk) * 100 + n];
    }
    wdT[idx] = f2bf(v);
  }
}

// ---------------- MFMA xz GEMM: out[combo][t][200] = A@Wx + b ----------------
template <int KP>
__global__ __launch_bounds__(256) void xz_mfma(
    const bf16t* __restrict__ A1, const bf16t* __restrict__ A2,
    const bf16t* __restrict__ WT,
    const float* __restrict__ bf_, const float* __restrict__ bb_,
    bf16t* __restrict__ out) {
  const int combo = blockIdx.y;
  const bf16t* __restrict__ A = (combo < 2) ? A1 : A2;
  const bf16t* __restrict__ W = WT + (size_t)(combo & 1) * 208 * KP;
  const float* __restrict__ bias = (combo & 1) ? bb_ : bf_;
  bf16t* __restrict__ O = out + (size_t)combo * TOKN * 200;
  const int tid = threadIdx.x;
  const int wave = tid >> 6, lane = tid & 63;
  const int m0 = blockIdx.x * 64 + wave * 16;
  const int l15 = lane & 15, quad = lane >> 4;
  floatx4 acc[13];
#pragma unroll
  for (int nt = 0; nt < 13; ++nt) acc[nt] = (floatx4){0.f, 0.f, 0.f, 0.f};
  const bf16t* __restrict__ arow = A + (size_t)(m0 + l15) * KP + quad * 8;
  const bf16t* __restrict__ wb = W + (size_t)l15 * KP + quad * 8;
#pragma unroll
  for (int ks = 0; ks < KP / 32; ++ks) {
    bf16x8 a = *(const bf16x8*)(arow + ks * 32);
#pragma unroll
    for (int nt = 0; nt < 13; ++nt) {
      bf16x8 b = *(const bf16x8*)(wb + (size_t)nt * 16 * KP + ks * 32);
      acc[nt] = __builtin_amdgcn_mfma_f32_16x16x32_bf16(a, b, acc[nt], 0, 0, 0);
    }
  }
  const int crow = m0 + quad * 4;
#pragma unroll
  for (int nt = 0; nt < 13; ++nt) {
    int n = nt * 16 + l15;
    if (n < 200) {
      float bn = bias[n];
#pragma unroll
      for (int r = 0; r < 4; ++r)
        O[(size_t)(crow + r) * 200 + n] = f2bf(acc[nt][r] + bn);
    }
  }
}

// ---------------- MFMA dense: map = relu([e,d,e*d]@W' + b), out [t][128] ----------------
__global__ __launch_bounds__(256) void dense_mfma(
    const bf16t* __restrict__ enc1, const bf16t* __restrict__ enc2,
    const bf16t* __restrict__ d1b, const bf16t* __restrict__ d2b,
    const bf16t* __restrict__ wdT, const float* __restrict__ bias,
    bf16t* __restrict__ map1, bf16t* __restrict__ map2) {
  const int inp = blockIdx.y;
  const bf16t* __restrict__ E = inp ? enc2 : enc1;
  const bf16t* __restrict__ Db = inp ? d2b : d1b;
  bf16t* __restrict__ O = inp ? map2 : map1;
  const int tid = threadIdx.x;
  const int wave = tid >> 6, lane = tid & 63;
  const int m0 = blockIdx.x * 64 + wave * 16;
  const int l15 = lane & 15, quad = lane >> 4;
  floatx4 acc[8];
#pragma unroll
  for (int nt = 0; nt < 8; ++nt) acc[nt] = (floatx4){0.f, 0.f, 0.f, 0.f};
  const bf16t* __restrict__ erow = E + (size_t)(m0 + l15) * 128 + quad * 8;
  const bf16t* __restrict__ drow = Db + (size_t)(m0 + l15) * 128 + quad * 8;
  const bf16t* __restrict__ wb = wdT + (size_t)l15 * 384 + quad * 8;
#pragma unroll
  for (int ks = 0; ks < 4; ++ks) {
    bf16x8 ae = *(const bf16x8*)(erow + ks * 32);
    bf16x8 ad = *(const bf16x8*)(drow + ks * 32);
    bf16x8 aed;
#pragma unroll
    for (int q = 0; q < 8; ++q) {
      float pe = bf2f((bf16t)ae[q]);
      float pd = bf2f((bf16t)ad[q]);
      aed[q] = (short)f2bf(pe * pd);
    }
#pragma unroll
    for (int nt = 0; nt < 8; ++nt) {
      const bf16t* wn = wb + (size_t)nt * 16 * 384 + ks * 32;
      bf16x8 b0 = *(const bf16x8*)(wn);
      acc[nt] = __builtin_amdgcn_mfma_f32_16x16x32_bf16(ae, b0, acc[nt], 0, 0, 0);
      bf16x8 b1 = *(const bf16x8*)(wn + 128);
      acc[nt] = __builtin_amdgcn_mfma_f32_16x16x32_bf16(ad, b1, acc[nt], 0, 0, 0);
      bf16x8 b2 = *(const bf16x8*)(wn + 256);
      acc[nt] = __builtin_amdgcn_mfma_f32_16x16x32_bf16(aed, b2, acc[nt], 0, 0, 0);
    }
  }
  const int crow = m0 + quad * 4;
#pragma unroll
  for (int nt = 0; nt < 8; ++nt) {
    int n = nt * 16 + l15;
    float bn = (n < 100) ? bias[n] : 0.f;
#pragma unroll
    for (int r = 0; r < 4; ++r) {
      float v = (n < 100) ? fmaxf(acc[nt][r] + bn, 0.f) : 0.f;
      O[(size_t)(crow + r) * 128 + n] = f2bf(v);
    }
  }
}

// ---------------- LSTM scan: one block per (scan, batch) ----------------
// Gate-major layout: thread 4u+g handles gate g (i,f,g,o) of unit u, i.e.
// xz/Wh column g*50+u.  Phase 2 uses in-quad shuffles (no act[] LDS, no 2nd
// barrier).  h kept in LDS as bf16, double-buffered -> 1 barrier/step and
// only 4 wide LDS reads per wave per step (was 50 scalar broadcasts).
__global__ __launch_bounds__(256) void lstm_scan(
    const bf16t* __restrict__ xz,
    const float* __restrict__ Whf, const float* __restrict__ Whb,
    bf16t* __restrict__ out1, bf16t* __restrict__ out2,
    const float* __restrict__ m1, const float* __restrict__ m2,
    int hasMask) {
  const int blk = blockIdx.x;
  const int scan = blk >> 7;
  const int b = blk & 127;
  const int inp = scan >> 1;
  const int dir = scan & 1;
  const float* __restrict__ Wh = dir ? Whb : Whf;
  const bf16t* __restrict__ xzs = xz + (size_t)scan * TOKN * 200 + (size_t)b * SQ * 200;
  bf16t* __restrict__ outRaw = (inp ? out2 : out1) + (size_t)b * SQ * 128;
  bf16t* __restrict__ outp = outRaw + dir * 50;
  const float* __restrict__ mk = (inp ? m2 : m1) + b * SQ;

  const int tid = threadIdx.x;
  const int lane = tid & 63;
  const int u = tid >> 2, g = tid & 3;        // unit, gate (i,f,g,o)
  const int col = g * 50 + u;                 // xz / Wh column
  __shared__ __align__(16) bf16t hb[2][64];   // bf16 h, double-buffered

  float whc[50];
  if (tid < 200) {
#pragma unroll
    for (int k = 0; k < 50; ++k) whc[k] = Wh[k * 200 + col];
  }
  // zero both h buffers
  if (tid < 128) ((bf16t*)hb)[tid] = 0;
  float c = 0.f;
  float z0 = 0.f, z1 = 0.f;
  if (tid < 200) {
    z0 = bf2f(xzs[(size_t)(dir ? (SQ - 1) : 0) * 200 + col]);
    z1 = bf2f(xzs[(size_t)(dir ? (SQ - 2) : 1) * 200 + col]);
  }
  __syncthreads();
  for (int t = 0; t < SQ; ++t) {
    int tp = (t + 2 < SQ) ? (t + 2) : (SQ - 1);
    int rowp = dir ? (SQ - 1 - tp) : tp;
    float znext = 0.f;
    if (tid < 200) {
      znext = bf2f(xzs[(size_t)rowp * 200 + col]);
      // --- z = z0 + h . whc, h read as 3x uint4 + 1 dword of packed bf16
      const uint4* hp = (const uint4*)&hb[t & 1][0];
      uint4 q0 = hp[0], q1 = hp[1], q2 = hp[2];
      unsigned qL = *(const unsigned*)&hb[t & 1][48];
      float za = z0, zb = 0.f, zc = 0.f, zd = 0.f;
      unsigned dw[13] = {q0.x, q0.y, q0.z, q0.w, q1.x, q1.y, q1.z, q1.w,
                         q2.x, q2.y, q2.z, q2.w, qL};
#pragma unroll
      for (int p = 0; p < 13; ++p) {
        float h0 = __uint_as_float(dw[p] << 16);
        float h1 = __uint_as_float(dw[p] & 0xFFFF0000u);
        if (p & 1) {
          zc = fmaf(h0, whc[2 * p], zc);
          zd = fmaf(h1, whc[2 * p + 1], zd);
        } else {
          za = fmaf(h0, whc[2 * p], za);
          if (p < 12) zb = fmaf(h1, whc[2 * p + 1], zb);
        }
      }
      float z = (za + zb) + (zc + zd);
      float a = (g == 2) ? tanhx(z) : sigm(z);
      // --- phase 2 via in-quad shuffles
      int base = lane & ~3;
      float ai = __shfl(a, base + 0);
      float af = __shfl(a, base + 1);
      float ag_ = __shfl(a, base + 2);
      float ao = __shfl(a, base + 3);
      if (g == 0) {
        c = af * c + ai * ag_;
        float hn = ao * tanhx(c);
        hb[(t + 1) & 1][u] = f2bf(hn);
        float mv = hasMask ? mk[t] : 1.f;
        outp[(size_t)t * 128 + u] = f2bf(hn * mv);
      }
    } else if (dir == 0 && tid < 214) {
      // zero K-pad columns 100..127 (dir0 block owns them)
      *(unsigned*)&outRaw[(size_t)t * 128 + 100 + 2 * (tid - 200)] = 0u;
    }
    __syncthreads();
    z0 = z1;
    z1 = znext;
  }
}

// ---------------- attention (per timestep s) ----------------
__global__ __launch_bounds__(256) void attn_kernel(
    const bf16t* __restrict__ enc1, const bf16t* __restrict__ enc2,
    const float* __restrict__ m1, const float* __restrict__ m2,
    bf16t* __restrict__ d1b, bf16t* __restrict__ d2b) {
  const int s = blockIdx.x;
  const int tid = threadIdx.x;
  __shared__ __align__(16) float E1[BB][DD];
  __shared__ __align__(16) float E2[BB + 1][DD];
  __shared__ __align__(16) float Ah[64][APAD];
  __shared__ float mk1[BB], mk2[BB];
  __shared__ float rden[64];

  for (int idx = tid; idx < BB * 50; idx += 256) {
    int i = idx / 50, dp = idx - i * 50;
    float2 v1 = ldpair(enc1 + ((size_t)i * SQ + s) * 128 + 2 * dp);
    E1[i][2 * dp] = v1.x;
    E1[i][2 * dp + 1] = v1.y;
    float2 v2 = ldpair(enc2 + ((size_t)i * SQ + s) * 128 + 2 * dp);
    E2[i][2 * dp] = v2.x;
    E2[i][2 * dp + 1] = v2.y;
  }
  if (tid < BB) {
    mk1[tid] = m1[tid * SQ + s];
    mk2[tid] = m2[tid * SQ + s];
  }
  __syncthreads();

  const int ti = tid >> 4, tjj = tid & 15;
  const int xj = tid & 127;
  const int xd0 = (tid >> 7) * 50;
  float N[50];
#pragma unroll
  for (int q = 0; q < 50; ++q) N[q] = 0.f;
  float Dacc = 0.f, M = -1e30f;

  for (int half = 0; half < 2; ++half) {
    const int r0 = half * 64;
    float acc[4][8];
#pragma unroll
    for (int ii = 0; ii < 4; ++ii)
#pragma unroll
      for (int jj = 0; jj < 8; ++jj) acc[ii][jj] = 0.f;
    for (int k = 0; k < DD; k += 4) {
      float4 a4[4], b4[8];
#pragma unroll
      for (int ii = 0; ii < 4; ++ii)
        a4[ii] = *(const float4*)&E1[r0 + 4 * ti + ii][k];
#pragma unroll
      for (int jj = 0; jj < 8; ++jj)
        b4[jj] = *(const float4*)&E2[tjj + 16 * jj][k];
#pragma unroll
      for (int ii = 0; ii < 4; ++ii)
#pragma unroll
        for (int jj = 0; jj < 8; ++jj)
          acc[ii][jj] += a4[ii].x * b4[jj].x + a4[ii].y * b4[jj].y +
                         a4[ii].z * b4[jj].z + a4[ii].w * b4[jj].w;
    }
#pragma unroll
    for (int ii = 0; ii < 4; ++ii)
#pragma unroll
      for (int jj = 0; jj < 8; ++jj)
        Ah[4 * ti + ii][tjj + 16 * jj] = acc[ii][jj];
    __syncthreads();

    {
      float lm = M;
      for (int i = 0; i < 64; ++i) lm = fmaxf(lm, Ah[i][xj]);
      float scale = __expf(M - lm);
      Dacc *= scale;
#pragma unroll
      for (int q = 0; q < 50; ++q) N[q] *= scale;
      for (int i = 0; i < 64; ++i) {
        float p = __expf(Ah[i][xj] - lm) * mk1[r0 + i];
        Dacc += p;
        const float2* e1p = (const float2*)&E1[r0 + i][xd0];
#pragma unroll
        for (int q = 0; q < 25; ++q) {
          float2 ev = e1p[q];
          N[2 * q] += p * ev.x;
          N[2 * q + 1] += p * ev.y;
        }
      }
      M = lm;
    }
    __syncthreads();

    {
      int row = tid >> 2, seg = tid & 3;
      float mx = -1e30f;
      for (int q = 0; q < 32; ++q) mx = fmaxf(mx, Ah[row][seg + 4 * q]);
      mx = fmaxf(mx, __shfl_xor(mx, 1));
      mx = fmaxf(mx, __shfl_xor(mx, 2));
      float sm = 0.f;
      for (int q = 0; q < 32; ++q) {
        int jc = seg + 4 * q;
        float p = __expf(Ah[row][jc] - mx) * mk2[jc];
        Ah[row][jc] = p;
        sm += p;
      }
      sm += __shfl_xor(sm, 1);
      sm += __shfl_xor(sm, 2);
      if (seg == 0) rden[row] = sm + 1e-8f;
    }
    __syncthreads();

    {
      float o[4][8];
#pragma unroll
      for (int ii = 0; ii < 4; ++ii)
#pragma unroll
        for (int jj = 0; jj < 8; ++jj) o[ii][jj] = 0.f;
      for (int jb = 0; jb < BB; ++jb) {
        float pv[4], ev[8];
#pragma unroll
        for (int ii = 0; ii < 4; ++ii) pv[ii] = Ah[4 * ti + ii][jb];
#pragma unroll
        for (int jj = 0; jj < 8; ++jj) ev[jj] = E2[jb][tjj + 16 * jj];
#pragma unroll
        for (int ii = 0; ii < 4; ++ii)
#pragma unroll
          for (int jj = 0; jj < 8; ++jj) o[ii][jj] += pv[ii] * ev[jj];
      }
#pragma unroll
      for (int ii = 0; ii < 4; ++ii) {
        int i = r0 + 4 * ti + ii;
        float inv = 1.f / rden[4 * ti + ii];
#pragma unroll
        for (int jj = 0; jj < 8; ++jj) {
          int d = tjj + 16 * jj;
          float val = (d < DD) ? o[ii][jj] * inv : 0.f;
          d1b[((size_t)i * SQ + s) * 128 + d] = f2bf(val);
        }
      }
    }
    __syncthreads();
  }
  float invD = 1.f / (Dacc + 1e-8f);
#pragma unroll
  for (int q = 0; q < 50; ++q)
    d2b[((size_t)xj * SQ + s) * 128 + xd0 + q] = f2bf(N[q] * invD);
  if (xd0 == 50) {
#pragma unroll
    for (int q = 0; q < 28; ++q)
      d2b[((size_t)xj * SQ + s) * 128 + 100 + q] = 0;
  }
}

// ---------------- masked pooling (cmp stride 128) ----------------
__global__ __launch_bounds__(128) void pool_kernel(
    const bf16t* __restrict__ cmp1, const bf16t* __restrict__ cmp2,
    const float* __restrict__ m1, const float* __restrict__ m2,
    float* __restrict__ pooled) {
  int b = blockIdx.x & 127, inp = blockIdx.x >> 7;
  const bf16t* C = (inp ? cmp2 : cmp1) + (size_t)b * SQ * 128;
  const float* M = (inp ? m2 : m1) + b * SQ;
  int f = threadIdx.x;
  float ms = 0.f;
  for (int s = f; s < SQ; s += 128) ms += M[s];
  __shared__ float red[128];
  red[f] = ms;
  __syncthreads();
  for (int o = 64; o > 0; o >>= 1) {
    if (f < o) red[f] += red[f + o];
    __syncthreads();
  }
  float msum = red[0];
  if (f < 100) {
    float sm = 0.f, mx = -1e30f;
    for (int s = 0; s < SQ; ++s) {
      float v = bf2f(C[(size_t)s * 128 + f]) * M[s];
      sm += v;
      mx = fmaxf(mx, v);
    }
    pooled[b * 400 + inp * 200 + f] = sm / msum;
    pooled[b * 400 + inp * 200 + 100 + f] = mx;
  }
}

// ---------------- final MLP + softmax ----------------
__global__ __launch_bounds__(128) void final_kernel(
    const float* __restrict__ pooled, const float* __restrict__ W1,
    const float* __restrict__ b1, const float* __restrict__ W2,
    const float* __restrict__ b2, float* __restrict__ out) {
  int b = blockIdx.x;
  int j = threadIdx.x;
  __shared__ float pr[400];
  __shared__ float h[100];
  for (int idx = j; idx < 400; idx += 128) pr[idx] = pooled[b * 400 + idx];
  __syncthreads();
  if (j < 100) {
    float a = b1[j];
    for (int k = 0; k < 400; ++k) a += pr[k] * W1[k * 100 + j];
    h[j] = tanhx(a);
  }
  __syncthreads();
  if (j == 0) {
    float l0 = b2[0], l1 = b2[1];
    for (int k = 0; k < 100; ++k) {
      l0 += h[k] * W2[k * 2];
      l1 += h[k] * W2[k * 2 + 1];
    }
    float mx = fmaxf(l0, l1);
    float e0 = __expf(l0 - mx), e1 = __expf(l1 - mx);
    float inv = 1.f / (e0 + e1);
    out[b * 2] = e0 * inv;
    out[b * 2 + 1] = e1 * inv;
  }
}

extern "C" void kernel_launch(void* const* d_in, const int* in_sizes, int n_in,
                              void* d_out, int out_size, void* d_ws, size_t ws_size,
                              hipStream_t stream) {
  const int* x1 = (const int*)d_in[0];
  const int* x2 = (const int*)d_in[1];
  const float* emb = (const float*)d_in[2];
  const float* b1f_Wx = (const float*)d_in[3];
  const float* b1f_Wh = (const float*)d_in[4];
  const float* b1f_b = (const float*)d_in[5];
  const float* b1b_Wx = (const float*)d_in[6];
  const float* b1b_Wh = (const float*)d_in[7];
  const float* b1b_b = (const float*)d_in[8];
  const float* dense_W = (const float*)d_in[9];
  const float* dense_b = (const float*)d_in[10];
  const float* b2f_Wx = (const float*)d_in[11];
  const float* b2f_Wh = (const float*)d_in[12];
  const float* b2f_b = (const float*)d_in[13];
  const float* b2b_Wx = (const float*)d_in[14];
  const float* b2b_Wh = (const float*)d_in[15];
  const float* b2b_b = (const float*)d_in[16];
  const float* dense1_W = (const float*)d_in[17];
  const float* dense1_b = (const float*)d_in[18];
  const float* out_W = (const float*)d_in[19];
  const float* out_b = (const float*)d_in[20];
  float* out = (float*)d_out;

  // ---- workspace layout (~173 MB) ----
  char* base = (char*)d_ws;
  bf16t* xz = (bf16t*)base;
  bf16t* d1b = (bf16t*)base;
  bf16t* d2b = d1b + (size_t)TOKN * 128;
  char* r1 = base + (size_t)4 * TOKN * 200 * 2;
  bf16t* enc1 = (bf16t*)r1;
  bf16t* enc2 = enc1 + (size_t)TOKN * 128;
  bf16t* e1b = (bf16t*)r1;
  bf16t* e2b = e1b + (size_t)TOKN * 64;
  char* r2 = r1 + (size_t)2 * TOKN * 128 * 2;
  bf16t* map1 = (bf16t*)r2;
  bf16t* map2 = map1 + (size_t)TOKN * 128;
  char* r3 = r2 + (size_t)2 * TOKN * 128 * 2;
  float* m1 = (float*)r3;
  float* m2 = m1 + TOKN;
  float* pooled = m2 + TOKN;
  bf16t* w1T = (bf16t*)(r3 + ((size_t)2 * TOKN + 128 * 400) * 4);
  bf16t* w2T = w1T + 2 * 208 * 64;
  bf16t* wdT = w2T + 2 * 208 * 128;
  bf16t* cmp1 = enc1;
  bf16t* cmp2 = enc2;
  (void)in_sizes; (void)n_in; (void)out_size; (void)ws_size;

  embed_kernel<<<dim3(TOKN * 64 / 256, 2), 256, 0, stream>>>(
      x1, x2, emb, e1b, e2b, m1, m2);
  wprep_kernel<<<dim3(208, 3), 256, 0, stream>>>(
      b1f_Wx, b1b_Wx, b2f_Wx, b2b_Wx, dense_W, w1T, w2T, wdT);
  xz_mfma<64><<<dim3(TOKN / 64, 4), 256, 0, stream>>>(
      e1b, e2b, w1T, b1f_b, b1b_b, xz);
  lstm_scan<<<512, 256, 0, stream>>>(xz, b1f_Wh, b1b_Wh, enc1, enc2, m1, m2, 1);
  attn_kernel<<<SQ, 256, 0, stream>>>(enc1, enc2, m1, m2, d1b, d2b);
  dense_mfma<<<dim3(TOKN / 64, 2), 256, 0, stream>>>(
      enc1, enc2, d1b, d2b, wdT, dense_b, map1, map2);
  xz_mfma<128><<<dim3(TOKN / 64, 4), 256, 0, stream>>>(
      map1, map2, w2T, b2f_b, b2b_b, xz);
  lstm_scan<<<512, 256, 0, stream>>>(xz, b2f_Wh, b2b_Wh, cmp1, cmp2, m1, m2, 0);
  pool_kernel<<<256, 128, 0, stream>>>(cmp1, cmp2, m1, m2, pooled);
  final_kernel<<<128, 128, 0, stream>>>(pooled, dense1_W, dense1_b, out_W, out_b, out);
}